// Round 2
// baseline (3708.053 us; speedup 1.0000x reference)
//
#include <hip/hip_runtime.h>
#include <math.h>

#define N_NODES 100000
#define N_EDGES 300000
#define N_GRAPHS 2048
#define HIDDEN 256
#define NODE_IN 64
#define N_LAYERS 3
#define LN_EPS 1e-5f
#define GTILE 32

typedef __attribute__((ext_vector_type(8))) short bf16x8;
typedef __attribute__((ext_vector_type(4))) float f32x4;

__device__ __forceinline__ float silu_f(float x) {
    return x / (1.f + expf(-x));
}

__device__ __forceinline__ short f2bf(float f) {
    union { float f; unsigned u; } v; v.f = f;
    unsigned r = v.u + 0x7fffu + ((v.u >> 16) & 1u);
    return (short)(r >> 16);
}

// h = silu(x @ W_in + b_in)   [N_NODES, HIDDEN]
__global__ __launch_bounds__(256) void input_proj(
        const float* __restrict__ x, const float* __restrict__ Win,
        const float* __restrict__ bin, float* __restrict__ h) {
    __shared__ __align__(16) float Wl[NODE_IN * HIDDEN];  // 64 KB
    __shared__ float xr[NODE_IN];
    const int t = threadIdx.x;
    for (int i = t; i < NODE_IN * HIDDEN; i += 256) Wl[i] = Win[i];
    const float bias = bin[t];
    __syncthreads();
    for (int node = blockIdx.x; node < N_NODES; node += gridDim.x) {
        if (t < NODE_IN) xr[t] = x[node * NODE_IN + t];
        __syncthreads();
        float acc = bias;
        #pragma unroll
        for (int k0 = 0; k0 < NODE_IN; k0 += 4) {
            float4 a = *reinterpret_cast<const float4*>(&xr[k0]);
            acc += a.x * Wl[(k0 + 0) * HIDDEN + t];
            acc += a.y * Wl[(k0 + 1) * HIDDEN + t];
            acc += a.z * Wl[(k0 + 2) * HIDDEN + t];
            acc += a.w * Wl[(k0 + 3) * HIDDEN + t];
        }
        h[(size_t)node * HIDDEN + t] = silu_f(acc);
        __syncthreads();
    }
}

// Wt[l][n][k] = bf16(W[l][k][n])  -- so B-fragments are contiguous in k
__global__ __launch_bounds__(256) void prep_wt(
        const float* __restrict__ W, short* __restrict__ Wt) {
    const int l = blockIdx.x >> 8;
    const int n = blockIdx.x & 255;
    const int k = threadIdx.x;
    Wt[((size_t)l * 256 + n) * 256 + k] = f2bf(W[((size_t)l * 256 + k) * 256 + n]);
}

// msg[dst] += relu(h[src]); one wave per edge, float4 per lane
__global__ __launch_bounds__(256) void scatter_relu4(
        const float* __restrict__ h, const int* __restrict__ src,
        const int* __restrict__ dst, float* __restrict__ msg) {
    const int e = blockIdx.x * 4 + (threadIdx.x >> 6);
    const int l = threadIdx.x & 63;
    const int s = src[e];
    const int d = dst[e];
    float4 v = *reinterpret_cast<const float4*>(&h[(size_t)s * HIDDEN + l * 4]);
    float* mp = &msg[(size_t)d * HIDDEN + l * 4];
    if (v.x > 0.f) atomicAdd(mp + 0, v.x);
    if (v.y > 0.f) atomicAdd(mp + 1, v.y);
    if (v.z > 0.f) atomicAdd(mp + 2, v.z);
    if (v.w > 0.f) atomicAdd(mp + 3, v.w);
}

// out = silu(LN((h + msg) @ W + b) * gamma + beta) + h   via bf16 MFMA
// 32 rows x 256 cols per block, 4 waves (each wave: 64 cols, 2x4 16x16 tiles)
__global__ __launch_bounds__(256) void gemm_ln_mfma(
        const float* __restrict__ h, const float* __restrict__ msg,
        const short* __restrict__ Wt, const float* __restrict__ bias,
        const float* __restrict__ gamma, const float* __restrict__ beta,
        float* __restrict__ out) {
    // union: A-tile bf16 [32][256] (16 KB, XOR-swizzled) then h2 f32 [32][260]
    __shared__ __align__(16) char smem[GTILE * 260 * 4];
    __shared__ float mu_s[GTILE], rs_s[GTILE];

    const int t = threadIdx.x;
    const size_t base = (size_t)blockIdx.x * GTILE * HIDDEN;

    // ---- stage: A = bf16(h + msg), residual h kept in registers ----
    const int srow = t >> 3;        // 0..31
    const int scg  = t & 7;         // col group of 32
    const size_t rowbase = base + (size_t)srow * HIDDEN + scg * 32;
    float hres[32];
    short abf[32];
    #pragma unroll
    for (int i = 0; i < 8; ++i) {
        float4 hv = *reinterpret_cast<const float4*>(&h[rowbase + i * 4]);
        float4 mv = *reinterpret_cast<const float4*>(&msg[rowbase + i * 4]);
        hres[i * 4 + 0] = hv.x; hres[i * 4 + 1] = hv.y;
        hres[i * 4 + 2] = hv.z; hres[i * 4 + 3] = hv.w;
        abf[i * 4 + 0] = f2bf(hv.x + mv.x);
        abf[i * 4 + 1] = f2bf(hv.y + mv.y);
        abf[i * 4 + 2] = f2bf(hv.z + mv.z);
        abf[i * 4 + 3] = f2bf(hv.w + mv.w);
    }
    #pragma unroll
    for (int j = 0; j < 4; ++j) {
        const int boff = srow * 512 + ((scg * 64 + j * 16) ^ ((srow & 7) << 4));
        *reinterpret_cast<bf16x8*>(smem + boff) =
            *reinterpret_cast<const bf16x8*>(&abf[j * 8]);
    }
    __syncthreads();

    // ---- MFMA: 2 row-tiles x 4 col-tiles per wave, K = 8 x 32 ----
    const int w  = t >> 6;
    const int l  = t & 63;
    const int lr = l & 15;
    const int g  = l >> 4;
    f32x4 acc[2][4] = {};

    const short* wbase = Wt + (size_t)(w * 64 + lr) * 256 + g * 8;
    #pragma unroll
    for (int kt = 0; kt < 8; ++kt) {
        const int aoff = ((kt * 64 + g * 16) ^ ((lr & 7) << 4));
        bf16x8 a0 = *reinterpret_cast<const bf16x8*>(smem + lr * 512 + aoff);
        bf16x8 a1 = *reinterpret_cast<const bf16x8*>(smem + (16 + lr) * 512 + aoff);
        #pragma unroll
        for (int ct = 0; ct < 4; ++ct) {
            bf16x8 bf = *reinterpret_cast<const bf16x8*>(wbase + (size_t)ct * 16 * 256 + kt * 32);
            acc[0][ct] = __builtin_amdgcn_mfma_f32_16x16x32_bf16(a0, bf, acc[0][ct], 0, 0, 0);
            acc[1][ct] = __builtin_amdgcn_mfma_f32_16x16x32_bf16(a1, bf, acc[1][ct], 0, 0, 0);
        }
    }
    __syncthreads();   // done reading A-tile; smem becomes h2 f32 [32][260]

    // ---- write h2 = acc + bias ----
    float* h2 = reinterpret_cast<float*>(smem);
    #pragma unroll
    for (int ct = 0; ct < 4; ++ct) {
        const int col = w * 64 + ct * 16 + lr;
        const float bs = bias[col];
        #pragma unroll
        for (int rt = 0; rt < 2; ++rt) {
            #pragma unroll
            for (int j = 0; j < 4; ++j) {
                const int row = rt * 16 + g * 4 + j;
                h2[row * 260 + col] = acc[rt][ct][j] + bs;
            }
        }
    }
    __syncthreads();

    // ---- LN stats: 8 threads per row ----
    {
        const int n = t >> 3, j = t & 7;
        float s = 0.f;
        #pragma unroll
        for (int i = 0; i < HIDDEN / 8; ++i) s += h2[n * 260 + j + 8 * i];
        s += __shfl_xor(s, 1); s += __shfl_xor(s, 2); s += __shfl_xor(s, 4);
        const float mu = s * (1.f / HIDDEN);
        float v = 0.f;
        #pragma unroll
        for (int i = 0; i < HIDDEN / 8; ++i) {
            float d = h2[n * 260 + j + 8 * i] - mu;
            v += d * d;
        }
        v += __shfl_xor(v, 1); v += __shfl_xor(v, 2); v += __shfl_xor(v, 4);
        if (j == 0) {
            mu_s[n] = mu;
            rs_s[n] = rsqrtf(v * (1.f / HIDDEN) + LN_EPS);
        }
    }
    __syncthreads();

    // ---- epilogue: out = silu(LN) + h ----
    const float mu = mu_s[srow], rs = rs_s[srow];
    #pragma unroll
    for (int i = 0; i < 8; ++i) {
        const int c0 = scg * 32 + i * 4;
        float4 gmv = *reinterpret_cast<const float4*>(&gamma[c0]);
        float4 btv = *reinterpret_cast<const float4*>(&beta[c0]);
        float4 o;
        o.x = silu_f((h2[srow * 260 + c0 + 0] - mu) * rs * gmv.x + btv.x) + hres[i * 4 + 0];
        o.y = silu_f((h2[srow * 260 + c0 + 1] - mu) * rs * gmv.y + btv.y) + hres[i * 4 + 1];
        o.z = silu_f((h2[srow * 260 + c0 + 2] - mu) * rs * gmv.z + btv.z) + hres[i * 4 + 2];
        o.w = silu_f((h2[srow * 260 + c0 + 3] - mu) * rs * gmv.w + btv.w) + hres[i * 4 + 3];
        *reinterpret_cast<float4*>(&out[rowbase + i * 4]) = o;
    }
}

// global mean pool over sorted batch_ids; one block per graph
__global__ __launch_bounds__(256) void pool_mean(
        const float* __restrict__ h, const int* __restrict__ bid,
        float* __restrict__ out) {
    const int g = blockIdx.x, t = threadIdx.x;
    int lo = 0, hi = N_NODES;
    while (lo < hi) { int mid = (lo + hi) >> 1; if (bid[mid] < g) lo = mid + 1; else hi = mid; }
    const int start = lo;
    hi = N_NODES;
    while (lo < hi) { int mid = (lo + hi) >> 1; if (bid[mid] < g + 1) lo = mid + 1; else hi = mid; }
    const int end = lo;
    float s = 0.f;
    for (int n = start; n < end; ++n) s += h[(size_t)n * HIDDEN + t];
    const float cnt = (float)(end - start);
    out[(size_t)g * HIDDEN + t] = s / fmaxf(cnt, 1.f);
}

extern "C" void kernel_launch(void* const* d_in, const int* in_sizes, int n_in,
                              void* d_out, int out_size, void* d_ws, size_t ws_size,
                              hipStream_t stream) {
    const float* x     = (const float*)d_in[0];
    const int*   ei    = (const int*)d_in[1];
    const int*   bid   = (const int*)d_in[2];
    const float* Win   = (const float*)d_in[3];
    const float* bin   = (const float*)d_in[4];
    const float* W     = (const float*)d_in[5];
    const float* b     = (const float*)d_in[6];
    const float* gamma = (const float*)d_in[7];
    const float* beta  = (const float*)d_in[8];
    float* out = (float*)d_out;

    const size_t hb = (size_t)N_NODES * HIDDEN * sizeof(float);
    float* A = (float*)d_ws;
    float* B = A + (size_t)N_NODES * HIDDEN;
    const size_t wtb = (size_t)N_LAYERS * HIDDEN * HIDDEN * sizeof(short);
    short* Wt = (ws_size >= 2 * hb + wtb)
              ? (short*)((char*)d_ws + 2 * hb)
              : (short*)d_out;   // d_out (2 MB) as scratch; pool overwrites it last

    const int* src = ei;
    const int* dst = ei + N_EDGES;

    prep_wt<<<N_LAYERS * 256, 256, 0, stream>>>(W, Wt);
    input_proj<<<2048, 256, 0, stream>>>(x, Win, bin, A);

    float* cur = A;
    float* alt = B;
    for (int l = 0; l < N_LAYERS; ++l) {
        hipMemsetAsync(alt, 0, hb, stream);
        scatter_relu4<<<N_EDGES / 4, 256, 0, stream>>>(cur, src, dst, alt);
        gemm_ln_mfma<<<N_NODES / GTILE, 256, 0, stream>>>(
            cur, alt, Wt + (size_t)l * HIDDEN * HIDDEN,
            b + (size_t)l * HIDDEN, gamma + (size_t)l * HIDDEN,
            beta + (size_t)l * HIDDEN, alt);
        float* tmp = cur; cur = alt; alt = tmp;
    }
    pool_mean<<<N_GRAPHS, 256, 0, stream>>>(cur, bid, out);
}

// Round 4
// 994.035 us; speedup vs baseline: 3.7303x; 3.7303x over previous
//
#include <hip/hip_runtime.h>
#include <math.h>

#define N_NODES 100000
#define N_EDGES 300000
#define N_GRAPHS 2048
#define HIDDEN 256
#define NODE_IN 64
#define N_LAYERS 3
#define LN_EPS 1e-5f
#define GTILE 32
#define N_TILES (N_NODES / GTILE)   // 3125
#define BCAP 256                    // bucket capacity per tile (mean 96, ~16 sigma)

typedef __attribute__((ext_vector_type(8))) short bf16x8;
typedef __attribute__((ext_vector_type(4))) float f32x4;

__device__ __forceinline__ float silu_f(float x) {
    return x / (1.f + expf(-x));
}

__device__ __forceinline__ short f2bf(float f) {
    union { float f; unsigned u; } v; v.f = f;
    unsigned r = v.u + 0x7fffu + ((v.u >> 16) & 1u);
    return (short)(r >> 16);
}

// h = silu(x @ W_in + b_in)   [N_NODES, HIDDEN]
__global__ __launch_bounds__(256) void input_proj(
        const float* __restrict__ x, const float* __restrict__ Win,
        const float* __restrict__ bin, float* __restrict__ h) {
    __shared__ __align__(16) float Wl[NODE_IN * HIDDEN];  // 64 KB
    __shared__ float xr[NODE_IN];
    const int t = threadIdx.x;
    for (int i = t; i < NODE_IN * HIDDEN; i += 256) Wl[i] = Win[i];
    const float bias = bin[t];
    __syncthreads();
    for (int node = blockIdx.x; node < N_NODES; node += gridDim.x) {
        if (t < NODE_IN) xr[t] = x[node * NODE_IN + t];
        __syncthreads();
        float acc = bias;
        #pragma unroll
        for (int k0 = 0; k0 < NODE_IN; k0 += 4) {
            float4 a = *reinterpret_cast<const float4*>(&xr[k0]);
            acc += a.x * Wl[(k0 + 0) * HIDDEN + t];
            acc += a.y * Wl[(k0 + 1) * HIDDEN + t];
            acc += a.z * Wl[(k0 + 2) * HIDDEN + t];
            acc += a.w * Wl[(k0 + 3) * HIDDEN + t];
        }
        h[(size_t)node * HIDDEN + t] = silu_f(acc);
        __syncthreads();
    }
}

// Wt[l][n][k] = bf16(W[l][k][n])  -- so B-fragments are contiguous in k
__global__ __launch_bounds__(256) void prep_wt(
        const float* __restrict__ W, short* __restrict__ Wt) {
    const int l = blockIdx.x >> 8;
    const int n = blockIdx.x & 255;
    const int k = threadIdx.x;
    Wt[((size_t)l * 256 + n) * 256 + k] = f2bf(W[((size_t)l * 256 + k) * 256 + n]);
}

// bucket edges by 32-row destination tile; entry = (dst&31)<<17 | src
__global__ __launch_bounds__(256) void build_buckets(
        const int* __restrict__ src, const int* __restrict__ dst,
        int* __restrict__ cnt, int* __restrict__ bucket) {
    const int e = blockIdx.x * 256 + threadIdx.x;
    if (e >= N_EDGES) return;
    const int d = dst[e];
    const int s = src[e];
    const int tile = d >> 5;
    const int slot = atomicAdd(&cnt[tile], 1);
    if (slot < BCAP) bucket[tile * BCAP + slot] = ((d & 31) << 17) | s;
}

// Fused per-layer kernel:
//   agg = h + sum_{edges into row} relu(h[src])   (gathered via bucket, no atomics)
//   out = silu(LN(agg @ W + b) * gamma + beta) + h   via bf16 MFMA
// 32 rows x 256 cols per block, 4 waves.
__global__ __launch_bounds__(256) void layer_fused(
        const float* __restrict__ h, const int* __restrict__ cnt,
        const int* __restrict__ bucket,
        const short* __restrict__ Wt, const float* __restrict__ bias,
        const float* __restrict__ gamma, const float* __restrict__ beta,
        float* __restrict__ out) {
    // union: A-tile bf16 [32][256] (16 KB, XOR-swizzled) then h2 f32 [32][260]
    __shared__ __align__(16) char smem[GTILE * 260 * 4];
    __shared__ float mu_s[GTILE], rs_s[GTILE];
    __shared__ int ebuf[BCAP];

    const int t = threadIdx.x;
    const int b = blockIdx.x;
    const size_t base = (size_t)b * GTILE * HIDDEN;

    const int c = min(cnt[b], BCAP);
    for (int i = t; i < c; i += 256) ebuf[i] = bucket[b * BCAP + i];

    // ---- stage: macc = h(self) + sum relu(h[src]); residual h kept in regs ----
    const int srow = t >> 3;        // 0..31  (row within tile)
    const int scg  = t & 7;         // col group of 32
    const size_t rowbase = base + (size_t)srow * HIDDEN + scg * 32;
    float hres[32];
    float macc[32];
    #pragma unroll
    for (int i = 0; i < 8; ++i) {
        float4 hv = *reinterpret_cast<const float4*>(&h[rowbase + i * 4]);
        hres[i * 4 + 0] = hv.x; hres[i * 4 + 1] = hv.y;
        hres[i * 4 + 2] = hv.z; hres[i * 4 + 3] = hv.w;
        macc[i * 4 + 0] = hv.x; macc[i * 4 + 1] = hv.y;
        macc[i * 4 + 2] = hv.z; macc[i * 4 + 3] = hv.w;
    }
    __syncthreads();   // ebuf ready

    for (int i = 0; i < c; ++i) {
        const int entry = ebuf[i];          // LDS broadcast (free)
        if ((entry >> 17) == srow) {
            const int s = entry & 0x1FFFF;
            const float* hp = &h[(size_t)s * HIDDEN + scg * 32];
            #pragma unroll
            for (int j = 0; j < 8; ++j) {
                float4 v = *reinterpret_cast<const float4*>(&hp[j * 4]);
                macc[j * 4 + 0] += fmaxf(v.x, 0.f);
                macc[j * 4 + 1] += fmaxf(v.y, 0.f);
                macc[j * 4 + 2] += fmaxf(v.z, 0.f);
                macc[j * 4 + 3] += fmaxf(v.w, 0.f);
            }
        }
    }

    // write bf16 A-tile (XOR-swizzled rows of 512B)
    #pragma unroll
    for (int j = 0; j < 4; ++j) {
        short abf[8];
        #pragma unroll
        for (int k = 0; k < 8; ++k) abf[k] = f2bf(macc[j * 8 + k]);
        const int boff = srow * 512 + ((scg * 64 + j * 16) ^ ((srow & 7) << 4));
        *reinterpret_cast<bf16x8*>(smem + boff) =
            *reinterpret_cast<const bf16x8*>(abf);
    }
    __syncthreads();

    // ---- MFMA: 2 row-tiles x 4 col-tiles per wave, K = 8 x 32 ----
    const int w  = t >> 6;
    const int l  = t & 63;
    const int lr = l & 15;
    const int g  = l >> 4;
    f32x4 acc[2][4] = {};

    const short* wbase = Wt + (size_t)(w * 64 + lr) * 256 + g * 8;
    #pragma unroll
    for (int kt = 0; kt < 8; ++kt) {
        const int aoff = ((kt * 64 + g * 16) ^ ((lr & 7) << 4));
        bf16x8 a0 = *reinterpret_cast<const bf16x8*>(smem + lr * 512 + aoff);
        bf16x8 a1 = *reinterpret_cast<const bf16x8*>(smem + (16 + lr) * 512 + aoff);
        #pragma unroll
        for (int ct = 0; ct < 4; ++ct) {
            bf16x8 bf = *reinterpret_cast<const bf16x8*>(wbase + (size_t)ct * 16 * 256 + kt * 32);
            acc[0][ct] = __builtin_amdgcn_mfma_f32_16x16x32_bf16(a0, bf, acc[0][ct], 0, 0, 0);
            acc[1][ct] = __builtin_amdgcn_mfma_f32_16x16x32_bf16(a1, bf, acc[1][ct], 0, 0, 0);
        }
    }
    __syncthreads();   // done reading A-tile; smem becomes h2 f32 [32][260]

    // ---- write h2 = acc + bias ----
    float* h2 = reinterpret_cast<float*>(smem);
    #pragma unroll
    for (int ct = 0; ct < 4; ++ct) {
        const int col = w * 64 + ct * 16 + lr;
        const float bs = bias[col];
        #pragma unroll
        for (int rt = 0; rt < 2; ++rt) {
            #pragma unroll
            for (int j = 0; j < 4; ++j) {
                const int row = rt * 16 + g * 4 + j;
                h2[row * 260 + col] = acc[rt][ct][j] + bs;
            }
        }
    }
    __syncthreads();

    // ---- LN stats: 8 threads per row ----
    {
        const int n = t >> 3, j = t & 7;
        float s = 0.f;
        #pragma unroll
        for (int i = 0; i < HIDDEN / 8; ++i) s += h2[n * 260 + j + 8 * i];
        s += __shfl_xor(s, 1); s += __shfl_xor(s, 2); s += __shfl_xor(s, 4);
        const float mu = s * (1.f / HIDDEN);
        float v = 0.f;
        #pragma unroll
        for (int i = 0; i < HIDDEN / 8; ++i) {
            float d = h2[n * 260 + j + 8 * i] - mu;
            v += d * d;
        }
        v += __shfl_xor(v, 1); v += __shfl_xor(v, 2); v += __shfl_xor(v, 4);
        if (j == 0) {
            mu_s[n] = mu;
            rs_s[n] = rsqrtf(v * (1.f / HIDDEN) + LN_EPS);
        }
    }
    __syncthreads();

    // ---- epilogue: out = silu(LN) + h ----
    const float mu = mu_s[srow], rs = rs_s[srow];
    #pragma unroll
    for (int i = 0; i < 8; ++i) {
        const int c0 = scg * 32 + i * 4;
        float4 gmv = *reinterpret_cast<const float4*>(&gamma[c0]);
        float4 btv = *reinterpret_cast<const float4*>(&beta[c0]);
        float4 o;
        o.x = silu_f((h2[srow * 260 + c0 + 0] - mu) * rs * gmv.x + btv.x) + hres[i * 4 + 0];
        o.y = silu_f((h2[srow * 260 + c0 + 1] - mu) * rs * gmv.y + btv.y) + hres[i * 4 + 1];
        o.z = silu_f((h2[srow * 260 + c0 + 2] - mu) * rs * gmv.z + btv.z) + hres[i * 4 + 2];
        o.w = silu_f((h2[srow * 260 + c0 + 3] - mu) * rs * gmv.w + btv.w) + hres[i * 4 + 3];
        *reinterpret_cast<float4*>(&out[rowbase + i * 4]) = o;
    }
}

// global mean pool over sorted batch_ids; one block per graph
__global__ __launch_bounds__(256) void pool_mean(
        const float* __restrict__ h, const int* __restrict__ bid,
        float* __restrict__ out) {
    const int g = blockIdx.x, t = threadIdx.x;
    int lo = 0, hi = N_NODES;
    while (lo < hi) { int mid = (lo + hi) >> 1; if (bid[mid] < g) lo = mid + 1; else hi = mid; }
    const int start = lo;
    hi = N_NODES;
    while (lo < hi) { int mid = (lo + hi) >> 1; if (bid[mid] < g + 1) lo = mid + 1; else hi = mid; }
    const int end = lo;
    float s = 0.f;
    for (int n = start; n < end; ++n) s += h[(size_t)n * HIDDEN + t];
    const float cnt = (float)(end - start);
    out[(size_t)g * HIDDEN + t] = s / fmaxf(cnt, 1.f);
}

extern "C" void kernel_launch(void* const* d_in, const int* in_sizes, int n_in,
                              void* d_out, int out_size, void* d_ws, size_t ws_size,
                              hipStream_t stream) {
    const float* x     = (const float*)d_in[0];
    const int*   ei    = (const int*)d_in[1];
    const int*   bid   = (const int*)d_in[2];
    const float* Win   = (const float*)d_in[3];
    const float* bin   = (const float*)d_in[4];
    const float* W     = (const float*)d_in[5];
    const float* b     = (const float*)d_in[6];
    const float* gamma = (const float*)d_in[7];
    const float* beta  = (const float*)d_in[8];
    float* out = (float*)d_out;

    const size_t hElems = (size_t)N_NODES * HIDDEN;
    float* A  = (float*)d_ws;
    float* B  = A + hElems;
    short* Wt = (short*)(B + hElems);
    int* cnt    = (int*)(Wt + (size_t)N_LAYERS * HIDDEN * HIDDEN);
    int* bucket = cnt + N_TILES;

    const int* src = ei;
    const int* dst = ei + N_EDGES;

    hipMemsetAsync(cnt, 0, N_TILES * sizeof(int), stream);
    build_buckets<<<(N_EDGES + 255) / 256, 256, 0, stream>>>(src, dst, cnt, bucket);
    prep_wt<<<N_LAYERS * 256, 256, 0, stream>>>(W, Wt);
    input_proj<<<2048, 256, 0, stream>>>(x, Win, bin, A);

    float* cur = A;
    float* alt = B;
    for (int l = 0; l < N_LAYERS; ++l) {
        layer_fused<<<N_TILES, 256, 0, stream>>>(
            cur, cnt, bucket, Wt + (size_t)l * HIDDEN * HIDDEN,
            b + (size_t)l * HIDDEN, gamma + (size_t)l * HIDDEN,
            beta + (size_t)l * HIDDEN, alt);
        float* tmp = cur; cur = alt; alt = tmp;
    }
    pool_mean<<<N_GRAPHS, 256, 0, stream>>>(cur, bid, out);
}

// Round 5
// 815.397 us; speedup vs baseline: 4.5475x; 1.2191x over previous
//
#include <hip/hip_runtime.h>
#include <math.h>

#define N_NODES 100000
#define N_EDGES 300000
#define N_GRAPHS 2048
#define HIDDEN 256
#define NODE_IN 64
#define N_LAYERS 3
#define LN_EPS 1e-5f
#define GTILE 32
#define N_TILES (N_NODES / GTILE)   // 3125
#define BCAP 256                    // bucket capacity per tile (mean 96, ~16 sigma)

typedef __attribute__((ext_vector_type(8))) short bf16x8;
typedef __attribute__((ext_vector_type(4))) float f32x4;

__device__ __forceinline__ float silu_f(float x) {
    return x / (1.f + expf(-x));
}

__device__ __forceinline__ short f2bf(float f) {
    union { float f; unsigned u; } v; v.f = f;
    unsigned r = v.u + 0x7fffu + ((v.u >> 16) & 1u);
    return (short)(r >> 16);
}

// Wtin[n][k] = bf16(Win[k][n]), n in [0,256), k in [0,64)
__global__ __launch_bounds__(256) void prep_win(
        const float* __restrict__ Win, short* __restrict__ Wtin) {
    const int n = threadIdx.x;
    for (int k = 0; k < NODE_IN; ++k)
        Wtin[n * NODE_IN + k] = f2bf(Win[k * HIDDEN + n]);
}

// Wt[l][n][k] = bf16(W[l][k][n])  -- so B-fragments are contiguous in k
__global__ __launch_bounds__(256) void prep_wt(
        const float* __restrict__ W, short* __restrict__ Wt) {
    const int l = blockIdx.x >> 8;
    const int n = blockIdx.x & 255;
    const int k = threadIdx.x;
    Wt[((size_t)l * 256 + n) * 256 + k] = f2bf(W[((size_t)l * 256 + k) * 256 + n]);
}

// h = silu(x @ W_in + b_in) via bf16 MFMA; 32 rows x 256 cols per block
__global__ __launch_bounds__(256) void input_proj_mfma(
        const float* __restrict__ x, const short* __restrict__ Wtin,
        const float* __restrict__ bin, float* __restrict__ h) {
    __shared__ __align__(16) char alds[GTILE * NODE_IN * 2];  // 4 KB bf16 A-tile
    const int t = threadIdx.x;
    const int b = blockIdx.x;

    // ---- stage: A = bf16(x-tile), XOR-swizzled ----
    const int srow = t >> 3;       // 0..31
    const int skg  = t & 7;        // 16B slot (8 bf16) within 64-k row
    const size_t xbase = ((size_t)b * GTILE + srow) * NODE_IN + skg * 8;
    float4 v0 = *reinterpret_cast<const float4*>(&x[xbase]);
    float4 v1 = *reinterpret_cast<const float4*>(&x[xbase + 4]);
    short a8[8];
    a8[0] = f2bf(v0.x); a8[1] = f2bf(v0.y); a8[2] = f2bf(v0.z); a8[3] = f2bf(v0.w);
    a8[4] = f2bf(v1.x); a8[5] = f2bf(v1.y); a8[6] = f2bf(v1.z); a8[7] = f2bf(v1.w);
    const int boff = srow * 128 + ((skg * 16) ^ ((srow & 7) << 4));
    *reinterpret_cast<bf16x8*>(alds + boff) = *reinterpret_cast<const bf16x8*>(a8);
    __syncthreads();

    // ---- MFMA: 2 row-tiles x 4 col-tiles per wave, K = 2 x 32 ----
    const int w  = t >> 6;
    const int l  = t & 63;
    const int lr = l & 15;
    const int g  = l >> 4;
    f32x4 acc[2][4] = {};
    #pragma unroll
    for (int kt = 0; kt < 2; ++kt) {
        const int aoff = (kt * 64 + g * 16) ^ ((lr & 7) << 4);
        bf16x8 a0 = *reinterpret_cast<const bf16x8*>(alds + lr * 128 + aoff);
        bf16x8 a1 = *reinterpret_cast<const bf16x8*>(alds + (16 + lr) * 128 + aoff);
        #pragma unroll
        for (int ct = 0; ct < 4; ++ct) {
            bf16x8 bf = *reinterpret_cast<const bf16x8*>(
                Wtin + (w * 64 + ct * 16 + lr) * NODE_IN + kt * 32 + g * 8);
            acc[0][ct] = __builtin_amdgcn_mfma_f32_16x16x32_bf16(a0, bf, acc[0][ct], 0, 0, 0);
            acc[1][ct] = __builtin_amdgcn_mfma_f32_16x16x32_bf16(a1, bf, acc[1][ct], 0, 0, 0);
        }
    }

    // ---- epilogue: h = silu(acc + bias) ----
    #pragma unroll
    for (int ct = 0; ct < 4; ++ct) {
        const int col = w * 64 + ct * 16 + lr;
        const float bs = bin[col];
        #pragma unroll
        for (int rt = 0; rt < 2; ++rt) {
            #pragma unroll
            for (int j = 0; j < 4; ++j) {
                const int row = rt * 16 + g * 4 + j;
                h[((size_t)b * GTILE + row) * HIDDEN + col] = silu_f(acc[rt][ct][j] + bs);
            }
        }
    }
}

// bucket edges by 32-row destination tile; entry = (dst&31)<<17 | src
__global__ __launch_bounds__(256) void build_buckets(
        const int* __restrict__ src, const int* __restrict__ dst,
        int* __restrict__ cnt, int* __restrict__ bucket) {
    const int e = blockIdx.x * 256 + threadIdx.x;
    if (e >= N_EDGES) return;
    const int d = dst[e];
    const int s = src[e];
    const int tile = d >> 5;
    const int slot = atomicAdd(&cnt[tile], 1);
    if (slot < BCAP) bucket[tile * BCAP + slot] = ((d & 31) << 17) | s;
}

// Fused per-layer kernel:
//   agg = h + sum_{edges into row} relu(h[src])   (gathered via bucket, no atomics)
//   out = silu(LN(agg @ W + b) * gamma + beta) + h   via bf16 MFMA
// 32 rows x 256 cols per block, 4 waves.
__global__ __launch_bounds__(256) void layer_fused(
        const float* __restrict__ h, const int* __restrict__ cnt,
        const int* __restrict__ bucket,
        const short* __restrict__ Wt, const float* __restrict__ bias,
        const float* __restrict__ gamma, const float* __restrict__ beta,
        float* __restrict__ out) {
    // union: A-tile bf16 [32][256] (16 KB, XOR-swizzled) then h2 f32 [32][260]
    __shared__ __align__(16) char smem[GTILE * 260 * 4];
    __shared__ float mu_s[GTILE], rs_s[GTILE];
    __shared__ int ebuf[BCAP];

    const int t = threadIdx.x;
    const int b = blockIdx.x;
    const size_t base = (size_t)b * GTILE * HIDDEN;

    const int c = min(cnt[b], BCAP);
    for (int i = t; i < c; i += 256) ebuf[i] = bucket[b * BCAP + i];

    // ---- stage: macc = h(self) + sum relu(h[src]); residual h kept in regs ----
    const int srow = t >> 3;        // 0..31  (row within tile)
    const int scg  = t & 7;         // col group of 32
    const size_t rowbase = base + (size_t)srow * HIDDEN + scg * 32;
    float hres[32];
    float macc[32];
    #pragma unroll
    for (int i = 0; i < 8; ++i) {
        float4 hv = *reinterpret_cast<const float4*>(&h[rowbase + i * 4]);
        hres[i * 4 + 0] = hv.x; hres[i * 4 + 1] = hv.y;
        hres[i * 4 + 2] = hv.z; hres[i * 4 + 3] = hv.w;
        macc[i * 4 + 0] = hv.x; macc[i * 4 + 1] = hv.y;
        macc[i * 4 + 2] = hv.z; macc[i * 4 + 3] = hv.w;
    }
    __syncthreads();   // ebuf ready

    for (int i = 0; i < c; ++i) {
        const int entry = ebuf[i];          // LDS broadcast (free)
        if ((entry >> 17) == srow) {
            const int s = entry & 0x1FFFF;
            const float* hp = &h[(size_t)s * HIDDEN + scg * 32];
            #pragma unroll
            for (int j = 0; j < 8; ++j) {
                float4 v = *reinterpret_cast<const float4*>(&hp[j * 4]);
                macc[j * 4 + 0] += fmaxf(v.x, 0.f);
                macc[j * 4 + 1] += fmaxf(v.y, 0.f);
                macc[j * 4 + 2] += fmaxf(v.z, 0.f);
                macc[j * 4 + 3] += fmaxf(v.w, 0.f);
            }
        }
    }

    // write bf16 A-tile (XOR-swizzled rows of 512B)
    #pragma unroll
    for (int j = 0; j < 4; ++j) {
        short abf[8];
        #pragma unroll
        for (int k = 0; k < 8; ++k) abf[k] = f2bf(macc[j * 8 + k]);
        const int boff = srow * 512 + ((scg * 64 + j * 16) ^ ((srow & 7) << 4));
        *reinterpret_cast<bf16x8*>(smem + boff) =
            *reinterpret_cast<const bf16x8*>(abf);
    }
    __syncthreads();

    // ---- MFMA: 2 row-tiles x 4 col-tiles per wave, K = 8 x 32 ----
    const int w  = t >> 6;
    const int l  = t & 63;
    const int lr = l & 15;
    const int g  = l >> 4;
    f32x4 acc[2][4] = {};

    const short* wbase = Wt + (size_t)(w * 64 + lr) * 256 + g * 8;
    #pragma unroll
    for (int kt = 0; kt < 8; ++kt) {
        const int aoff = ((kt * 64 + g * 16) ^ ((lr & 7) << 4));
        bf16x8 a0 = *reinterpret_cast<const bf16x8*>(smem + lr * 512 + aoff);
        bf16x8 a1 = *reinterpret_cast<const bf16x8*>(smem + (16 + lr) * 512 + aoff);
        #pragma unroll
        for (int ct = 0; ct < 4; ++ct) {
            bf16x8 bf = *reinterpret_cast<const bf16x8*>(wbase + (size_t)ct * 16 * 256 + kt * 32);
            acc[0][ct] = __builtin_amdgcn_mfma_f32_16x16x32_bf16(a0, bf, acc[0][ct], 0, 0, 0);
            acc[1][ct] = __builtin_amdgcn_mfma_f32_16x16x32_bf16(a1, bf, acc[1][ct], 0, 0, 0);
        }
    }
    __syncthreads();   // done reading A-tile; smem becomes h2 f32 [32][260]

    // ---- write h2 = acc + bias ----
    float* h2 = reinterpret_cast<float*>(smem);
    #pragma unroll
    for (int ct = 0; ct < 4; ++ct) {
        const int col = w * 64 + ct * 16 + lr;
        const float bs = bias[col];
        #pragma unroll
        for (int rt = 0; rt < 2; ++rt) {
            #pragma unroll
            for (int j = 0; j < 4; ++j) {
                const int row = rt * 16 + g * 4 + j;
                h2[row * 260 + col] = acc[rt][ct][j] + bs;
            }
        }
    }
    __syncthreads();

    // ---- LN stats: 8 threads per row ----
    {
        const int n = t >> 3, j = t & 7;
        float s = 0.f;
        #pragma unroll
        for (int i = 0; i < HIDDEN / 8; ++i) s += h2[n * 260 + j + 8 * i];
        s += __shfl_xor(s, 1); s += __shfl_xor(s, 2); s += __shfl_xor(s, 4);
        const float mu = s * (1.f / HIDDEN);
        float v = 0.f;
        #pragma unroll
        for (int i = 0; i < HIDDEN / 8; ++i) {
            float d = h2[n * 260 + j + 8 * i] - mu;
            v += d * d;
        }
        v += __shfl_xor(v, 1); v += __shfl_xor(v, 2); v += __shfl_xor(v, 4);
        if (j == 0) {
            mu_s[n] = mu;
            rs_s[n] = rsqrtf(v * (1.f / HIDDEN) + LN_EPS);
        }
    }
    __syncthreads();

    // ---- epilogue: out = silu(LN) + h ----
    const float mu = mu_s[srow], rs = rs_s[srow];
    #pragma unroll
    for (int i = 0; i < 8; ++i) {
        const int c0 = scg * 32 + i * 4;
        float4 gmv = *reinterpret_cast<const float4*>(&gamma[c0]);
        float4 btv = *reinterpret_cast<const float4*>(&beta[c0]);
        float4 o;
        o.x = silu_f((h2[srow * 260 + c0 + 0] - mu) * rs * gmv.x + btv.x) + hres[i * 4 + 0];
        o.y = silu_f((h2[srow * 260 + c0 + 1] - mu) * rs * gmv.y + btv.y) + hres[i * 4 + 1];
        o.z = silu_f((h2[srow * 260 + c0 + 2] - mu) * rs * gmv.z + btv.z) + hres[i * 4 + 2];
        o.w = silu_f((h2[srow * 260 + c0 + 3] - mu) * rs * gmv.w + btv.w) + hres[i * 4 + 3];
        *reinterpret_cast<float4*>(&out[rowbase + i * 4]) = o;
    }
}

// global mean pool over sorted batch_ids; one block per graph
__global__ __launch_bounds__(256) void pool_mean(
        const float* __restrict__ h, const int* __restrict__ bid,
        float* __restrict__ out) {
    const int g = blockIdx.x, t = threadIdx.x;
    int lo = 0, hi = N_NODES;
    while (lo < hi) { int mid = (lo + hi) >> 1; if (bid[mid] < g) lo = mid + 1; else hi = mid; }
    const int start = lo;
    hi = N_NODES;
    while (lo < hi) { int mid = (lo + hi) >> 1; if (bid[mid] < g + 1) lo = mid + 1; else hi = mid; }
    const int end = lo;
    float s = 0.f;
    for (int n = start; n < end; ++n) s += h[(size_t)n * HIDDEN + t];
    const float cnt = (float)(end - start);
    out[(size_t)g * HIDDEN + t] = s / fmaxf(cnt, 1.f);
}

extern "C" void kernel_launch(void* const* d_in, const int* in_sizes, int n_in,
                              void* d_out, int out_size, void* d_ws, size_t ws_size,
                              hipStream_t stream) {
    const float* x     = (const float*)d_in[0];
    const int*   ei    = (const int*)d_in[1];
    const int*   bid   = (const int*)d_in[2];
    const float* Win   = (const float*)d_in[3];
    const float* bin   = (const float*)d_in[4];
    const float* W     = (const float*)d_in[5];
    const float* b     = (const float*)d_in[6];
    const float* gamma = (const float*)d_in[7];
    const float* beta  = (const float*)d_in[8];
    float* out = (float*)d_out;

    const size_t hElems = (size_t)N_NODES * HIDDEN;
    float* A  = (float*)d_ws;
    float* B  = A + hElems;
    short* Wt = (short*)(B + hElems);
    int* cnt    = (int*)(Wt + (size_t)N_LAYERS * HIDDEN * HIDDEN);
    int* bucket = cnt + N_TILES;
    short* Wtin = (short*)(bucket + (size_t)N_TILES * BCAP);

    const int* src = ei;
    const int* dst = ei + N_EDGES;

    hipMemsetAsync(cnt, 0, N_TILES * sizeof(int), stream);
    build_buckets<<<(N_EDGES + 255) / 256, 256, 0, stream>>>(src, dst, cnt, bucket);
    prep_win<<<1, 256, 0, stream>>>(Win, Wtin);
    prep_wt<<<N_LAYERS * 256, 256, 0, stream>>>(W, Wt);
    input_proj_mfma<<<N_TILES, 256, 0, stream>>>(x, Wtin, bin, A);

    float* cur = A;
    float* alt = B;
    for (int l = 0; l < N_LAYERS; ++l) {
        layer_fused<<<N_TILES, 256, 0, stream>>>(
            cur, cnt, bucket, Wt + (size_t)l * HIDDEN * HIDDEN,
            b + (size_t)l * HIDDEN, gamma + (size_t)l * HIDDEN,
            beta + (size_t)l * HIDDEN, alt);
        float* tmp = cur; cur = alt; alt = tmp;
    }
    pool_mean<<<N_GRAPHS, 256, 0, stream>>>(cur, bid, out);
}